// Round 3
// baseline (554.963 us; speedup 1.0000x reference)
//
#include <hip/hip_runtime.h>
#include <hip/hip_bf16.h>

#define S_LEN 2048
#define HID 4096
#define NH 32
#define NKV 8
#define HD 128

typedef unsigned short u16;
typedef __attribute__((ext_vector_type(4))) float f32x4;
typedef __attribute__((ext_vector_type(8))) short bf16x8;

__device__ __forceinline__ u16 f2bf(float x) {
  union { float f; unsigned u; } c; c.f = x;
  unsigned r = c.u + 0x7FFFu + ((c.u >> 16) & 1u);
  return (u16)(r >> 16);
}

__device__ __forceinline__ void gload16(const void* g, void* l) {
  __builtin_amdgcn_global_load_lds(
      (const __attribute__((address_space(1))) unsigned int*)g,
      (__attribute__((address_space(3))) unsigned int*)l, 16, 0, 0);
}

// ---------------- fp32 -> bf16 convert (float4 / ushort4) ----------------
__global__ void cvt4_kernel(const float* __restrict__ s, u16* __restrict__ d, int n4) {
  int i = blockIdx.x * 256 + threadIdx.x;
  if (i >= n4) return;
  float4 v = ((const float4*)s)[i];
  ushort4 o;
  o.x = f2bf(v.x); o.y = f2bf(v.y); o.z = f2bf(v.z); o.w = f2bf(v.w);
  ((ushort4*)d)[i] = o;
}

// ---------------- rope cos/sin table [S][64] ----------------
__global__ void rope_tab_kernel(float2* __restrict__ tab) {
  int i = blockIdx.x * 256 + threadIdx.x; // S*64
  int t = i >> 6, d = i & 63;
  float inv = expf(-(float)d * (11.512925464970229f / 64.0f));
  float f = (float)t * inv;
  float2 cs; cs.x = cosf(f); cs.y = sinf(f);
  tab[i] = cs;
}

// ---------------- Q rope (pre-scaled by log2e/sqrt(D)): qkv fp32 -> Q bf16 [S][NH][128] ----------------
__global__ void rope_q_kernel(const float* __restrict__ qkv, const float2* __restrict__ tab,
                              u16* __restrict__ Q) {
  int i = blockIdx.x * 256 + threadIdx.x; // S*NH*64
  int d = i & 63, h = (i >> 6) & 31, t = i >> 11;
  const float* row = qkv + (size_t)t * 6144 + h * 128;
  float x1 = row[d], x2 = row[d + 64];
  float2 cs = tab[(t << 6) | d];
  const float SC = 0.12752551286084f; // (1/sqrt(128)) * log2(e)
  u16* orow = Q + (((size_t)t * NH + h) << 7);
  orow[d]      = f2bf((x1 * cs.x - x2 * cs.y) * SC);
  orow[d + 64] = f2bf((x1 * cs.y + x2 * cs.x) * SC);
}

// ---------------- K conv(2)+rope: -> K bf16 [S][NKV][128] ----------------
__global__ void convrope_k_kernel(const float* __restrict__ qkv, const float* __restrict__ ck,
                                  const float2* __restrict__ tab, u16* __restrict__ K) {
  int i = blockIdx.x * 256 + threadIdx.x; // S*NKV*64
  int d = i & 63, kv = (i >> 6) & 7, t = i >> 9;
  const float* cur = qkv + (size_t)t * 6144 + 4096 + kv * 128;
  float c0 = ck[kv * 2], c1 = ck[kv * 2 + 1];
  float x1 = c1 * cur[d], x2 = c1 * cur[d + 64];
  if (t > 0) { const float* prv = cur - 6144; x1 += c0 * prv[d]; x2 += c0 * prv[d + 64]; }
  float2 cs = tab[(t << 6) | d];
  u16* orow = K + (((size_t)t * NKV + kv) << 7);
  orow[d]      = f2bf(x1 * cs.x - x2 * cs.y);
  orow[d + 64] = f2bf(x1 * cs.y + x2 * cs.x);
}

// ---------------- V conv(2) + transpose: -> VT bf16 [NKV][128][S] ----------------
__global__ __launch_bounds__(256) void convT_v_kernel(const float* __restrict__ qkv,
                                                      const float* __restrict__ cv,
                                                      u16* __restrict__ VT) {
  __shared__ float ld[65][128];
  int tt = blockIdx.x * 64, kv = blockIdx.y;
  float c0 = cv[kv * 2], c1 = cv[kv * 2 + 1];
  for (int idx = threadIdx.x; idx < 65 * 128; idx += 256) {
    int r = idx >> 7, d = idx & 127;
    int t = tt - 1 + r;
    ld[r][d] = (t >= 0) ? qkv[(size_t)t * 6144 + 5120 + kv * 128 + d] : 0.f;
  }
  __syncthreads();
  int d = threadIdx.x >> 1, tc = (threadIdx.x & 1) * 32;
  u16* out = VT + ((size_t)kv * 128 + d) * S_LEN + tt + tc;
#pragma unroll
  for (int j = 0; j < 32; ++j)
    out[j] = f2bf(c0 * ld[tc + j][d] + c1 * ld[tc + j + 1][d]);
}

// ---------------- NT GEMM: C[m,n] = sum_k A[m,k]*B[n,k]  (bf16 in, fp32 out) ----------------
#define BM 128
#define BN 128
#define BK 64

__global__ __launch_bounds__(256, 2) void gemm_nt_kernel(const u16* __restrict__ A,
                                                         const u16* __restrict__ B,
                                                         float* __restrict__ C,
                                                         int M, int N, int K) {
  __shared__ __align__(16) u16 lA[BM * BK];
  __shared__ __align__(16) u16 lB[BN * BK];
  const int tid = threadIdx.x;
  const int wid = tid >> 6, lane = tid & 63;
  // XCD-aware bijective swizzle (nwg % 8 == 0 for all our grids):
  // launched id L -> XCD L%8 gets contiguous work chunk.
  const int nbx = gridDim.x, nwg = nbx * gridDim.y;
  const int L = blockIdx.y * nbx + blockIdx.x;
  const int cpx = nwg >> 3;
  const int W = (L & 7) * cpx + (L >> 3);
  const int bm = (W / nbx) * BM, bn = (W % nbx) * BN;
  const int wr = (wid >> 1) * 64, wc = (wid & 1) * 64;
  const int lr = lane & 15, lg = lane >> 4;
  f32x4 acc[4][4] = {};
  const char* Ab = (const char*)A;
  const char* Bb = (const char*)B;
  const int nk = K / BK;
  for (int kt = 0; kt < nk; ++kt) {
    const size_t k0b = (size_t)kt * (BK * 2);
    __syncthreads();
#pragma unroll
    for (int i = 0; i < 4; ++i) {
      int off = (i * 4 + wid) * 1024 + lane * 16;
      int row = off >> 7, inrow = off & 127;
      int sw = inrow ^ ((row & 7) << 4);
      gload16(Ab + (size_t)(bm + row) * (K * 2) + k0b + sw, (char*)lA + (i * 4 + wid) * 1024);
      gload16(Bb + (size_t)(bn + row) * (K * 2) + k0b + sw, (char*)lB + (i * 4 + wid) * 1024);
    }
    __syncthreads();
    bf16x8 af[4][2], bfv[4][2];
#pragma unroll
    for (int m = 0; m < 4; ++m)
#pragma unroll
      for (int ks = 0; ks < 2; ++ks) {
        int row = wr + m * 16 + lr;
        int boff = row * 128 + ((ks * 64 + lg * 16) ^ ((row & 7) << 4));
        af[m][ks] = *(const bf16x8*)((const char*)lA + boff);
      }
#pragma unroll
    for (int n = 0; n < 4; ++n)
#pragma unroll
      for (int ks = 0; ks < 2; ++ks) {
        int row = wc + n * 16 + lr;
        int boff = row * 128 + ((ks * 64 + lg * 16) ^ ((row & 7) << 4));
        bfv[n][ks] = *(const bf16x8*)((const char*)lB + boff);
      }
#pragma unroll
    for (int m = 0; m < 4; ++m)
#pragma unroll
      for (int n = 0; n < 4; ++n)
#pragma unroll
        for (int ks = 0; ks < 2; ++ks)
          acc[m][n] = __builtin_amdgcn_mfma_f32_16x16x32_bf16(af[m][ks], bfv[n][ks], acc[m][n], 0, 0, 0);
  }
#pragma unroll
  for (int m = 0; m < 4; ++m)
#pragma unroll
    for (int n = 0; n < 4; ++n)
#pragma unroll
      for (int r = 0; r < 4; ++r) {
        int row = bm + wr + m * 16 + lg * 4 + r;
        int col = bn + wc + n * 16 + lr;
        C[(size_t)row * N + col] = acc[m][n][r];
      }
}

// ---------------- causal GQA flash attention ----------------
// Q: [S][NH][128] bf16 (pre-scaled), K: [S][NKV][128] bf16, VT: [NKV][128][S] bf16
// O: [S][NH*128] bf16. grid = (16, NH).
// Block covers q-tiles qtA=q0 and qtB=31-q0 (64 rows each). Waves 0,1 -> tile A
// (rows w2*32..+31), waves 2,3 -> tile B. Each wave: 32 q-rows = 2 MFMA row-frags,
// so K/V fragments are shared across 2 q-frags (halves LDS reads per q-row).
__global__ __launch_bounds__(256, 2) void attn_kernel(const u16* __restrict__ Q,
                                                      const u16* __restrict__ K,
                                                      const u16* __restrict__ VT,
                                                      u16* __restrict__ O) {
  __shared__ __align__(16) u16 lK[2][64 * 128];   // [t][d], 256B rows, XOR swizzled
  __shared__ __align__(16) u16 lV[2][128 * 64];   // [d][t], 128B rows, XOR swizzled
  __shared__ __align__(16) u16 lP[4][32 * 64];    // per-wave P, 128B rows, XOR swizzled
  const int tid = threadIdx.x;
  const int wid = tid >> 6, lane = tid & 63;
  const int lr = lane & 15, lg = lane >> 4;
  const int q0 = blockIdx.x, h = blockIdx.y;
  const int kvh = h >> 2;
  const int qtA = q0, qtB = 31 - q0;
  const int tile = wid >> 1, w2 = wid & 1;
  const int qt = tile ? qtB : qtA;
  const int qbase = qt * 64 + w2 * 32;

  bf16x8 qf[2][4];
#pragma unroll
  for (int m = 0; m < 2; ++m)
#pragma unroll
    for (int ks = 0; ks < 4; ++ks)
      qf[m][ks] = *(const bf16x8*)(Q + (((size_t)(qbase + m * 16 + lr) * NH + h) << 7) + ks * 32 + lg * 8);

  f32x4 o[2][8] = {};
  float mrow[2][4], lrow[2][4];
#pragma unroll
  for (int m = 0; m < 2; ++m)
#pragma unroll
    for (int r = 0; r < 4; ++r) { mrow[m][r] = -1e30f; lrow[m][r] = 0.f; }

  const char* Kb = (const char*)K;
  const char* Vb = (const char*)VT;
  char* pb = (char*)lP[wid];

  auto stage = [&](int buf, int kt) {
    char* dK = (char*)lK[buf];
    char* dV = (char*)lV[buf];
#pragma unroll
    for (int i = 0; i < 4; ++i) {
      int off = (i * 4 + wid) * 1024 + lane * 16;
      int t = off >> 8, inrow = off & 255;
      gload16(Kb + (((size_t)((kt * 64 + t) * NKV + kvh)) << 8) + (inrow ^ ((t & 7) << 4)),
              dK + (i * 4 + wid) * 1024);
      int d = off >> 7, inr2 = off & 127;
      gload16(Vb + ((size_t)(kvh * 128 + d)) * (S_LEN * 2) + kt * 128 + (inr2 ^ ((d & 7) << 4)),
              dV + (i * 4 + wid) * 1024);
    }
  };

  auto step = [&](int buf, bool diag) {
    const char* kb = (const char*)lK[buf];
    const char* vb = (const char*)lV[buf];
    // S = Q K^T: 32 q-rows x 64 k-cols per wave; K-frags shared across 2 q-frags.
    f32x4 sv[2][4] = {};
#pragma unroll
    for (int n = 0; n < 4; ++n)
#pragma unroll
      for (int ks = 0; ks < 4; ++ks) {
        int trow = n * 16 + lr;
        int boff = trow * 256 + ((ks * 64 + lg * 16) ^ ((trow & 7) << 4));
        bf16x8 kf = *(const bf16x8*)(kb + boff);
        sv[0][n] = __builtin_amdgcn_mfma_f32_16x16x32_bf16(qf[0][ks], kf, sv[0][n], 0, 0, 0);
        sv[1][n] = __builtin_amdgcn_mfma_f32_16x16x32_bf16(qf[1][ks], kf, sv[1][n], 0, 0, 0);
      }
    if (diag) {
#pragma unroll
      for (int m = 0; m < 2; ++m)
#pragma unroll
        for (int n = 0; n < 4; ++n)
#pragma unroll
          for (int r = 0; r < 4; ++r) {
            int col = n * 16 + lr, rw = w2 * 32 + m * 16 + lg * 4 + r;
            if (col > rw) sv[m][n][r] = -1e30f;
          }
    }
    // row max over 64 cols
    float pm[2][4];
#pragma unroll
    for (int m = 0; m < 2; ++m)
#pragma unroll
      for (int r = 0; r < 4; ++r) {
        float v = fmaxf(fmaxf(sv[m][0][r], sv[m][1][r]), fmaxf(sv[m][2][r], sv[m][3][r]));
        v = fmaxf(v, __shfl_xor(v, 1));
        v = fmaxf(v, __shfl_xor(v, 2));
        v = fmaxf(v, __shfl_xor(v, 4));
        v = fmaxf(v, __shfl_xor(v, 8));
        pm[m][r] = v;
      }
    // defer-max: rescale only when some row grew past THR=8 (log2 units)
    bool need = false;
#pragma unroll
    for (int m = 0; m < 2; ++m)
#pragma unroll
      for (int r = 0; r < 4; ++r)
        need |= (pm[m][r] > mrow[m][r] + 8.f);
    if (__any(need)) {
#pragma unroll
      for (int m = 0; m < 2; ++m)
#pragma unroll
        for (int r = 0; r < 4; ++r) {
          float mn = fmaxf(mrow[m][r], pm[m][r]);
          float al = exp2f(mrow[m][r] - mn);
          mrow[m][r] = mn;
          lrow[m][r] *= al;
#pragma unroll
          for (int nt = 0; nt < 8; ++nt) o[m][nt][r] *= al;
        }
    }
    // P = exp2(sv - m) -> wave-private LDS (A-layout), accumulate row sums
#pragma unroll
    for (int m = 0; m < 2; ++m) {
      float rs[4] = {0.f, 0.f, 0.f, 0.f};
#pragma unroll
      for (int n = 0; n < 4; ++n)
#pragma unroll
        for (int r = 0; r < 4; ++r) {
          float p = exp2f(sv[m][n][r] - mrow[m][r]);
          rs[r] += p;
          int row = m * 16 + lg * 4 + r, col = n * 16 + lr;
          int boff = (row * 128 + col * 2) ^ ((row & 7) << 4);
          *(u16*)(pb + boff) = f2bf(p);
        }
#pragma unroll
      for (int r = 0; r < 4; ++r) {
        float v = rs[r];
        v += __shfl_xor(v, 1);
        v += __shfl_xor(v, 2);
        v += __shfl_xor(v, 4);
        v += __shfl_xor(v, 8);
        lrow[m][r] += v;
      }
    }
    // O += P * V; V-frags shared across 2 q-frags
#pragma unroll
    for (int ks = 0; ks < 2; ++ks) {
      bf16x8 pf[2];
#pragma unroll
      for (int m = 0; m < 2; ++m) {
        int prow = m * 16 + lr;
        int aboff = prow * 128 + ((ks * 64 + lg * 16) ^ ((prow & 7) << 4));
        pf[m] = *(const bf16x8*)(pb + aboff);
      }
#pragma unroll
      for (int nt = 0; nt < 8; ++nt) {
        int drow = nt * 16 + lr;
        int vboff = drow * 128 + ((ks * 64 + lg * 16) ^ ((drow & 7) << 4));
        bf16x8 vf = *(const bf16x8*)(vb + vboff);
        o[0][nt] = __builtin_amdgcn_mfma_f32_16x16x32_bf16(pf[0], vf, o[0][nt], 0, 0, 0);
        o[1][nt] = __builtin_amdgcn_mfma_f32_16x16x32_bf16(pf[1], vf, o[1][nt], 0, 0, 0);
      }
    }
  };

  stage(0, 0);
  __syncthreads();
  for (int kt = 0; kt <= qtB; ++kt) {
    int cur = kt & 1;
    if (kt < qtB) stage(cur ^ 1, kt + 1);
    if (kt <= qt) step(cur, kt == qt);
    __syncthreads();
  }

#pragma unroll
  for (int m = 0; m < 2; ++m)
#pragma unroll
    for (int r = 0; r < 4; ++r) lrow[m][r] = 1.0f / lrow[m][r];
#pragma unroll
  for (int m = 0; m < 2; ++m)
#pragma unroll
    for (int nt = 0; nt < 8; ++nt)
#pragma unroll
      for (int r = 0; r < 4; ++r) {
        int row = qbase + m * 16 + lg * 4 + r;
        int col = nt * 16 + lr;
        O[(size_t)row * 4096 + h * 128 + col] = f2bf(o[m][nt][r] * lrow[m][r]);
      }
}

extern "C" void kernel_launch(void* const* d_in, const int* in_sizes, int n_in,
                              void* d_out, int out_size, void* d_ws, size_t ws_size,
                              hipStream_t stream) {
  const float* hidden = (const float*)d_in[0];
  const float* wpack  = (const float*)d_in[1];
  const float* wo     = (const float*)d_in[2];
  const float* convk  = (const float*)d_in[3];
  const float* convv  = (const float*)d_in[4];
  float* out = (float*)d_out;

  char* w = (char*)d_ws;
  u16*  hiddenB = (u16*)w;                   // 16,777,216 B (later reused as attn_out)
  u16*  wpackB  = (u16*)(w + 16777216);      // 50,331,648 B (later reused for w_o bf16)
  float* qkv    = (float*)(w + 67108864);    // 50,331,648 B
  u16*  qrope   = (u16*)(w + 117440512);     // 16,777,216 B
  u16*  krope   = (u16*)(w + 134217728);     //  4,194,304 B
  u16*  vT      = (u16*)(w + 138412032);     //  4,194,304 B
  float2* tab   = (float2*)(w + 142606336);  //  1,048,576 B

  cvt4_kernel<<<8192, 256, 0, stream>>>(hidden, hiddenB, 2097152);
  cvt4_kernel<<<24576, 256, 0, stream>>>(wpack, wpackB, 6291456);
  rope_tab_kernel<<<512, 256, 0, stream>>>(tab);
  gemm_nt_kernel<<<dim3(48, 16), 256, 0, stream>>>(hiddenB, wpackB, qkv, 2048, 6144, 4096);
  cvt4_kernel<<<16384, 256, 0, stream>>>(wo, wpackB, 4194304); // reuse wpackB for w_o bf16
  rope_q_kernel<<<16384, 256, 0, stream>>>(qkv, tab, qrope);
  convrope_k_kernel<<<4096, 256, 0, stream>>>(qkv, convk, tab, krope);
  convT_v_kernel<<<dim3(32, 8), 256, 0, stream>>>(qkv, convv, vT);
  attn_kernel<<<dim3(16, 32), 256, 0, stream>>>(qrope, krope, vT, hiddenB); // attn_out -> hiddenB
  gemm_nt_kernel<<<dim3(32, 16), 256, 0, stream>>>(hiddenB, wpackB, out, 2048, 4096, 4096);
}

// Round 4
// 529.699 us; speedup vs baseline: 1.0477x; 1.0477x over previous
//
#include <hip/hip_runtime.h>
#include <hip/hip_bf16.h>

#define S_LEN 2048
#define HID 4096
#define NH 32
#define NKV 8
#define HD 128

typedef unsigned short u16;
typedef __attribute__((ext_vector_type(4))) float f32x4;
typedef __attribute__((ext_vector_type(8))) short bf16x8;

__device__ __forceinline__ u16 f2bf(float x) {
  union { float f; unsigned u; } c; c.f = x;
  unsigned r = c.u + 0x7FFFu + ((c.u >> 16) & 1u);
  return (u16)(r >> 16);
}

__device__ __forceinline__ void gload16(const void* g, void* l) {
  __builtin_amdgcn_global_load_lds(
      (const __attribute__((address_space(1))) unsigned int*)g,
      (__attribute__((address_space(3))) unsigned int*)l, 16, 0, 0);
}

__device__ __forceinline__ unsigned cvtpk_bf16(float lo, float hi) {
  unsigned r;
  asm("v_cvt_pk_bf16_f32 %0, %1, %2" : "=v"(r) : "v"(lo), "v"(hi));
  return r;
}

__device__ __forceinline__ float bcastf(float v, int srclane) {
  int r = __builtin_amdgcn_ds_bpermute(srclane << 2, __builtin_bit_cast(int, v));
  return __builtin_bit_cast(float, r);
}

// ---------------- fp32 -> bf16 convert (float4 / ushort4) ----------------
__global__ void cvt4_kernel(const float* __restrict__ s, u16* __restrict__ d, int n4) {
  int i = blockIdx.x * 256 + threadIdx.x;
  if (i >= n4) return;
  float4 v = ((const float4*)s)[i];
  ushort4 o;
  o.x = f2bf(v.x); o.y = f2bf(v.y); o.z = f2bf(v.z); o.w = f2bf(v.w);
  ((ushort4*)d)[i] = o;
}

// ---------------- rope cos/sin table [S][64] ----------------
__global__ void rope_tab_kernel(float2* __restrict__ tab) {
  int i = blockIdx.x * 256 + threadIdx.x; // S*64
  int t = i >> 6, d = i & 63;
  float inv = expf(-(float)d * (11.512925464970229f / 64.0f));
  float f = (float)t * inv;
  float2 cs; cs.x = cosf(f); cs.y = sinf(f);
  tab[i] = cs;
}

// ---------------- Q rope (pre-scaled by log2e/sqrt(D)): qkv fp32 -> Q bf16 [S][NH][128] ----------------
__global__ void rope_q_kernel(const float* __restrict__ qkv, const float2* __restrict__ tab,
                              u16* __restrict__ Q) {
  int i = blockIdx.x * 256 + threadIdx.x; // S*NH*64
  int d = i & 63, h = (i >> 6) & 31, t = i >> 11;
  const float* row = qkv + (size_t)t * 6144 + h * 128;
  float x1 = row[d], x2 = row[d + 64];
  float2 cs = tab[(t << 6) | d];
  const float SC = 0.12752551286084f; // (1/sqrt(128)) * log2(e)
  u16* orow = Q + (((size_t)t * NH + h) << 7);
  orow[d]      = f2bf((x1 * cs.x - x2 * cs.y) * SC);
  orow[d + 64] = f2bf((x1 * cs.y + x2 * cs.x) * SC);
}

// ---------------- K conv(2)+rope: -> K bf16 [S][NKV][128] ----------------
__global__ void convrope_k_kernel(const float* __restrict__ qkv, const float* __restrict__ ck,
                                  const float2* __restrict__ tab, u16* __restrict__ K) {
  int i = blockIdx.x * 256 + threadIdx.x; // S*NKV*64
  int d = i & 63, kv = (i >> 6) & 7, t = i >> 9;
  const float* cur = qkv + (size_t)t * 6144 + 4096 + kv * 128;
  float c0 = ck[kv * 2], c1 = ck[kv * 2 + 1];
  float x1 = c1 * cur[d], x2 = c1 * cur[d + 64];
  if (t > 0) { const float* prv = cur - 6144; x1 += c0 * prv[d]; x2 += c0 * prv[d + 64]; }
  float2 cs = tab[(t << 6) | d];
  u16* orow = K + (((size_t)t * NKV + kv) << 7);
  orow[d]      = f2bf(x1 * cs.x - x2 * cs.y);
  orow[d + 64] = f2bf(x1 * cs.y + x2 * cs.x);
}

// ---------------- V conv(2) + transpose: -> VT bf16 [NKV][128][S] ----------------
__global__ __launch_bounds__(256) void convT_v_kernel(const float* __restrict__ qkv,
                                                      const float* __restrict__ cv,
                                                      u16* __restrict__ VT) {
  __shared__ float ld[65][128];
  int tt = blockIdx.x * 64, kv = blockIdx.y;
  float c0 = cv[kv * 2], c1 = cv[kv * 2 + 1];
  for (int idx = threadIdx.x; idx < 65 * 128; idx += 256) {
    int r = idx >> 7, d = idx & 127;
    int t = tt - 1 + r;
    ld[r][d] = (t >= 0) ? qkv[(size_t)t * 6144 + 5120 + kv * 128 + d] : 0.f;
  }
  __syncthreads();
  int d = threadIdx.x >> 1, tc = (threadIdx.x & 1) * 32;
  u16* out = VT + ((size_t)kv * 128 + d) * S_LEN + tt + tc;
#pragma unroll
  for (int j = 0; j < 32; ++j)
    out[j] = f2bf(c0 * ld[tc + j][d] + c1 * ld[tc + j + 1][d]);
}

// ---------------- NT GEMM: C[m,n] = sum_k A[m,k]*B[n,k]  (bf16 in, fp32 out) ----------------
#define BM 128
#define BN 128
#define BK 64

__global__ __launch_bounds__(256, 2) void gemm_nt_kernel(const u16* __restrict__ A,
                                                         const u16* __restrict__ B,
                                                         float* __restrict__ C,
                                                         int M, int N, int K) {
  __shared__ __align__(16) u16 lA[BM * BK];
  __shared__ __align__(16) u16 lB[BN * BK];
  const int tid = threadIdx.x;
  const int wid = tid >> 6, lane = tid & 63;
  const int nbx = gridDim.x, nwg = nbx * gridDim.y;
  const int L = blockIdx.y * nbx + blockIdx.x;
  const int cpx = nwg >> 3;
  const int W = (L & 7) * cpx + (L >> 3);
  const int bm = (W / nbx) * BM, bn = (W % nbx) * BN;
  const int wr = (wid >> 1) * 64, wc = (wid & 1) * 64;
  const int lr = lane & 15, lg = lane >> 4;
  f32x4 acc[4][4] = {};
  const char* Ab = (const char*)A;
  const char* Bb = (const char*)B;
  const int nk = K / BK;
  for (int kt = 0; kt < nk; ++kt) {
    const size_t k0b = (size_t)kt * (BK * 2);
    __syncthreads();
#pragma unroll
    for (int i = 0; i < 4; ++i) {
      int off = (i * 4 + wid) * 1024 + lane * 16;
      int row = off >> 7, inrow = off & 127;
      int sw = inrow ^ ((row & 7) << 4);
      gload16(Ab + (size_t)(bm + row) * (K * 2) + k0b + sw, (char*)lA + (i * 4 + wid) * 1024);
      gload16(Bb + (size_t)(bn + row) * (K * 2) + k0b + sw, (char*)lB + (i * 4 + wid) * 1024);
    }
    __syncthreads();
    bf16x8 af[4][2], bfv[4][2];
#pragma unroll
    for (int m = 0; m < 4; ++m)
#pragma unroll
      for (int ks = 0; ks < 2; ++ks) {
        int row = wr + m * 16 + lr;
        int boff = row * 128 + ((ks * 64 + lg * 16) ^ ((row & 7) << 4));
        af[m][ks] = *(const bf16x8*)((const char*)lA + boff);
      }
#pragma unroll
    for (int n = 0; n < 4; ++n)
#pragma unroll
      for (int ks = 0; ks < 2; ++ks) {
        int row = wc + n * 16 + lr;
        int boff = row * 128 + ((ks * 64 + lg * 16) ^ ((row & 7) << 4));
        bfv[n][ks] = *(const bf16x8*)((const char*)lB + boff);
      }
#pragma unroll
    for (int m = 0; m < 4; ++m)
#pragma unroll
      for (int n = 0; n < 4; ++n)
#pragma unroll
        for (int ks = 0; ks < 2; ++ks)
          acc[m][n] = __builtin_amdgcn_mfma_f32_16x16x32_bf16(af[m][ks], bfv[n][ks], acc[m][n], 0, 0, 0);
  }
#pragma unroll
  for (int m = 0; m < 4; ++m)
#pragma unroll
    for (int n = 0; n < 4; ++n)
#pragma unroll
      for (int r = 0; r < 4; ++r) {
        int row = bm + wr + m * 16 + lg * 4 + r;
        int col = bn + wc + n * 16 + lr;
        C[(size_t)row * N + col] = acc[m][n][r];
      }
}

// ---------------- causal GQA flash attention (swapped QK^T, adjacent-pair fusion) ----------------
// Q: [S][NH][128] bf16 (pre-scaled by log2e/sqrt(D)), K: [S][NKV][128] bf16, VT: [NKV][128][S] bf16
// O: [S][NH*128] bf16.
// grid = 512 1-D blocks. Block g -> head h, tile-pair b: tiles qtA=2b, qtB=2b+1 (64 rows each).
// Size-complementary mapping: blocks g and g+256 have step counts summing to 34 (CU balance).
// Each wave owns 16 rows of tile A AND 16 rows of tile B; all steps except the last are fused,
// sharing every K/V LDS fragment read across both tiles.
__global__ __launch_bounds__(256, 2) void attn_kernel(const u16* __restrict__ Q,
                                                      const u16* __restrict__ K,
                                                      const u16* __restrict__ VT,
                                                      u16* __restrict__ O) {
  __shared__ __align__(16) u16 lK[2][64 * 128];   // [t][d], 256B rows, XOR swizzled
  __shared__ __align__(16) u16 lV[2][128 * 64];   // [d][t], 128B rows, XOR swizzled
  __shared__ __align__(16) u16 lP[4][2][16 * 64]; // per-wave P[q][k], 128B rows, XOR swizzled
  const int tid = threadIdx.x;
  const int wid = tid >> 6, lane = tid & 63;
  const int lr = lane & 15, lg = lane >> 4;
  const int g = blockIdx.x;
  const int s = g & 255;
  const int h = s >> 3, j = s & 7;
  const int b = (g < 256) ? (15 - j) : j;
  const int kvh = h >> 2;
  const int qtA = 2 * b, qtB = 2 * b + 1;
  const int qrowA = qtA * 64 + wid * 16 + lr;  // this lane's q-row for tile A (softmax layout)
  const int qrowB = qtB * 64 + wid * 16 + lr;

  bf16x8 qfA[4], qfB[4];
#pragma unroll
  for (int ks = 0; ks < 4; ++ks) {
    qfA[ks] = *(const bf16x8*)(Q + (((size_t)qrowA * NH + h) << 7) + ks * 32 + lg * 8);
    qfB[ks] = *(const bf16x8*)(Q + (((size_t)qrowB * NH + h) << 7) + ks * 32 + lg * 8);
  }

  f32x4 oA[8] = {}, oB[8] = {};
  float mA = -1e30f, sumA = 0.f, mB = -1e30f, sumB = 0.f;

  const char* Kb = (const char*)K;
  const char* Vb = (const char*)VT;
  char* pbA = (char*)lP[wid][0];
  char* pbB = (char*)lP[wid][1];

  auto stage = [&](int buf, int kt) {
    char* dK = (char*)lK[buf];
    char* dV = (char*)lV[buf];
#pragma unroll
    for (int i = 0; i < 4; ++i) {
      int off = (i * 4 + wid) * 1024 + lane * 16;
      int t = off >> 8, inrow = off & 255;
      gload16(Kb + (((size_t)((kt * 64 + t) * NKV + kvh)) << 8) + (inrow ^ ((t & 7) << 4)),
              dK + (i * 4 + wid) * 1024);
      int d = off >> 7, inr2 = off & 127;
      gload16(Vb + ((size_t)(kvh * 128 + d)) * (S_LEN * 2) + kt * 128 + (inr2 ^ ((d & 7) << 4)),
              dV + (i * 4 + wid) * 1024);
    }
  };

  // softmax on S^T fragments: lane holds 16 values (k = n*16+lg*4+r) for q-row `qrow`.
  auto smx = [&](f32x4* sv, float& mm, float& ll, f32x4* o, char* pbuf, bool diag, int qrow, int kt) {
    if (diag) {
#pragma unroll
      for (int n = 0; n < 4; ++n)
#pragma unroll
        for (int r = 0; r < 4; ++r) {
          int kg = kt * 64 + n * 16 + lg * 4 + r;
          if (kg > qrow) sv[n][r] = -1e30f;
        }
    }
    float pm = sv[0][0];
#pragma unroll
    for (int n = 0; n < 4; ++n)
#pragma unroll
      for (int r = 0; r < 4; ++r) pm = fmaxf(pm, sv[n][r]);
    pm = fmaxf(pm, __shfl_xor(pm, 16));
    pm = fmaxf(pm, __shfl_xor(pm, 32));
    if (__any(pm > mm + 8.f)) {
      float mn = fmaxf(mm, pm);
      float al = exp2f(mm - mn);
      mm = mn;
      ll *= al;
      float alo[4];
#pragma unroll
      for (int r = 0; r < 4; ++r) alo[r] = bcastf(al, lg * 4 + r);
#pragma unroll
      for (int nt = 0; nt < 8; ++nt)
#pragma unroll
        for (int r = 0; r < 4; ++r) o[nt][r] *= alo[r];
    }
    float rs = 0.f;
#pragma unroll
    for (int n = 0; n < 4; ++n)
#pragma unroll
      for (int r = 0; r < 4; ++r) {
        float p = exp2f(sv[n][r] - mm);
        sv[n][r] = p;
        rs += p;
      }
    rs += __shfl_xor(rs, 16);
    rs += __shfl_xor(rs, 32);
    ll += rs;
    // pack to bf16 pairs, write P[q=lr][k = n*16+lg*4 .. +3] as one b64
#pragma unroll
    for (int n = 0; n < 4; ++n) {
      uint2 w;
      w.x = cvtpk_bf16(sv[n][0], sv[n][1]);
      w.y = cvtpk_bf16(sv[n][2], sv[n][3]);
      *(uint2*)(pbuf + ((lr * 128 + n * 32 + lg * 8) ^ ((lr & 7) << 4))) = w;
    }
  };

  stage(0, 0);
  __syncthreads();
  for (int kt = 0; kt <= qtB; ++kt) {
    int cur = kt & 1;
    if (kt < qtB) stage(cur ^ 1, kt + 1);
    const char* kb = (const char*)lK[cur];
    const char* vb = (const char*)lV[cur];
    const bool doA = (kt <= qtA);

    // QK^T swapped: sv = mfma(K-frag as A, Q-frag as B) -> S^T[k][q], q = lr
    f32x4 svA[4], svB[4];
#pragma unroll
    for (int n = 0; n < 4; ++n) {
      f32x4 aA = {}, aB = {};
#pragma unroll
      for (int ks = 0; ks < 4; ++ks) {
        int trow = n * 16 + lr;
        int boff = trow * 256 + ((ks * 64 + lg * 16) ^ ((trow & 7) << 4));
        bf16x8 kf = *(const bf16x8*)(kb + boff);
        aB = __builtin_amdgcn_mfma_f32_16x16x32_bf16(kf, qfB[ks], aB, 0, 0, 0);
        aA = __builtin_amdgcn_mfma_f32_16x16x32_bf16(kf, qfA[ks], aA, 0, 0, 0);
      }
      svA[n] = aA; svB[n] = aB;
    }

    if (doA) smx(svA, mA, sumA, oA, pbA, kt == qtA, qrowA, kt);
    smx(svB, mB, sumB, oB, pbB, kt == qtB, qrowB, kt);

    // O += P * V ; V-frags shared across tiles
#pragma unroll
    for (int ks = 0; ks < 2; ++ks) {
      int poff = (lr * 128 + 64 * ks + 16 * lg) ^ ((lr & 7) << 4);
      bf16x8 pfB = *(const bf16x8*)(pbB + poff);
      bf16x8 pfA = *(const bf16x8*)(pbA + poff);
#pragma unroll
      for (int nt = 0; nt < 8; ++nt) {
        int drow = nt * 16 + lr;
        int vboff = drow * 128 + ((ks * 64 + lg * 16) ^ ((drow & 7) << 4));
        bf16x8 vf = *(const bf16x8*)(vb + vboff);
        oB[nt] = __builtin_amdgcn_mfma_f32_16x16x32_bf16(pfB, vf, oB[nt], 0, 0, 0);
        if (doA) oA[nt] = __builtin_amdgcn_mfma_f32_16x16x32_bf16(pfA, vf, oA[nt], 0, 0, 0);
      }
    }
    __syncthreads();
  }

  float riA = 1.0f / sumA, riB = 1.0f / sumB;
  float rA[4], rB[4];
#pragma unroll
  for (int r = 0; r < 4; ++r) {
    rA[r] = bcastf(riA, lg * 4 + r);
    rB[r] = bcastf(riB, lg * 4 + r);
  }
#pragma unroll
  for (int nt = 0; nt < 8; ++nt)
#pragma unroll
    for (int r = 0; r < 4; ++r) {
      int rowA = qtA * 64 + wid * 16 + lg * 4 + r;
      int rowB = qtB * 64 + wid * 16 + lg * 4 + r;
      int col = nt * 16 + lr;
      O[(size_t)rowA * 4096 + h * 128 + col] = f2bf(oA[nt][r] * rA[r]);
      O[(size_t)rowB * 4096 + h * 128 + col] = f2bf(oB[nt][r] * rB[r]);
    }
}

extern "C" void kernel_launch(void* const* d_in, const int* in_sizes, int n_in,
                              void* d_out, int out_size, void* d_ws, size_t ws_size,
                              hipStream_t stream) {
  const float* hidden = (const float*)d_in[0];
  const float* wpack  = (const float*)d_in[1];
  const float* wo     = (const float*)d_in[2];
  const float* convk  = (const float*)d_in[3];
  const float* convv  = (const float*)d_in[4];
  float* out = (float*)d_out;

  char* w = (char*)d_ws;
  u16*  hiddenB = (u16*)w;                   // 16,777,216 B (later reused as attn_out)
  u16*  wpackB  = (u16*)(w + 16777216);      // 50,331,648 B (later reused for w_o bf16)
  float* qkv    = (float*)(w + 67108864);    // 50,331,648 B
  u16*  qrope   = (u16*)(w + 117440512);     // 16,777,216 B
  u16*  krope   = (u16*)(w + 134217728);     //  4,194,304 B
  u16*  vT      = (u16*)(w + 138412032);     //  4,194,304 B
  float2* tab   = (float2*)(w + 142606336);  //  1,048,576 B

  cvt4_kernel<<<8192, 256, 0, stream>>>(hidden, hiddenB, 2097152);
  cvt4_kernel<<<24576, 256, 0, stream>>>(wpack, wpackB, 6291456);
  rope_tab_kernel<<<512, 256, 0, stream>>>(tab);
  gemm_nt_kernel<<<dim3(48, 16), 256, 0, stream>>>(hiddenB, wpackB, qkv, 2048, 6144, 4096);
  cvt4_kernel<<<16384, 256, 0, stream>>>(wo, wpackB, 4194304); // reuse wpackB for w_o bf16
  rope_q_kernel<<<16384, 256, 0, stream>>>(qkv, tab, qrope);
  convrope_k_kernel<<<4096, 256, 0, stream>>>(qkv, convk, tab, krope);
  convT_v_kernel<<<dim3(32, 8), 256, 0, stream>>>(qkv, convv, vT);
  attn_kernel<<<512, 256, 0, stream>>>(qrope, krope, vT, hiddenB); // attn_out -> hiddenB
  gemm_nt_kernel<<<dim3(32, 16), 256, 0, stream>>>(hiddenB, wpackB, out, 2048, 4096, 4096);
}

// Round 5
// 485.665 us; speedup vs baseline: 1.1427x; 1.0907x over previous
//
#include <hip/hip_runtime.h>
#include <hip/hip_bf16.h>

#define S_LEN 2048
#define HID 4096
#define NH 32
#define NKV 8
#define HD 128

typedef unsigned short u16;
typedef __attribute__((ext_vector_type(4))) float f32x4;
typedef __attribute__((ext_vector_type(8))) short bf16x8;

__device__ __forceinline__ u16 f2bf(float x) {
  union { float f; unsigned u; } c; c.f = x;
  unsigned r = c.u + 0x7FFFu + ((c.u >> 16) & 1u);
  return (u16)(r >> 16);
}

__device__ __forceinline__ float bf2f(u16 x) {
  union { unsigned u; float f; } c; c.u = (unsigned)x << 16;
  return c.f;
}

__device__ __forceinline__ void gload16(const void* g, void* l) {
  __builtin_amdgcn_global_load_lds(
      (const __attribute__((address_space(1))) unsigned int*)g,
      (__attribute__((address_space(3))) unsigned int*)l, 16, 0, 0);
}

__device__ __forceinline__ unsigned cvtpk_bf16(float lo, float hi) {
  unsigned r;
  asm("v_cvt_pk_bf16_f32 %0, %1, %2" : "=v"(r) : "v"(lo), "v"(hi));
  return r;
}

__device__ __forceinline__ float bcastf(float v, int srclane) {
  int r = __builtin_amdgcn_ds_bpermute(srclane << 2, __builtin_bit_cast(int, v));
  return __builtin_bit_cast(float, r);
}

// ---------------- fp32 -> bf16 convert (float4 / ushort4) ----------------
__global__ void cvt4_kernel(const float* __restrict__ s, u16* __restrict__ d, int n4) {
  int i = blockIdx.x * 256 + threadIdx.x;
  if (i >= n4) return;
  float4 v = ((const float4*)s)[i];
  ushort4 o;
  o.x = f2bf(v.x); o.y = f2bf(v.y); o.z = f2bf(v.z); o.w = f2bf(v.w);
  ((ushort4*)d)[i] = o;
}

// ---------------- rope cos/sin table [S][64] ----------------
__global__ void rope_tab_kernel(float2* __restrict__ tab) {
  int i = blockIdx.x * 256 + threadIdx.x; // S*64
  int t = i >> 6, d = i & 63;
  float inv = expf(-(float)d * (11.512925464970229f / 64.0f));
  float f = (float)t * inv;
  float2 cs; cs.x = cosf(f); cs.y = sinf(f);
  tab[i] = cs;
}

// ---------------- Q rope (pre-scaled by log2e/sqrt(D)): qkv bf16 -> Q bf16 [S][NH][128] ----------------
__global__ void rope_q_kernel(const u16* __restrict__ qkv, const float* __restrict__ tab,
                              u16* __restrict__ Q) {
  int i = blockIdx.x * 256 + threadIdx.x; // S*NH*16
  int d4 = (i & 15) * 4, h = (i >> 4) & 31, t = i >> 9;
  const u16* row = qkv + (size_t)t * 6144 + h * 128;
  ushort4 a = *(const ushort4*)(row + d4);
  ushort4 b = *(const ushort4*)(row + d4 + 64);
  const float4* tf = (const float4*)(tab + ((t << 6) + d4) * 2);
  float4 c01 = tf[0], c23 = tf[1]; // (cos0,sin0,cos1,sin1),(cos2,sin2,cos3,sin3)
  const float SC = 0.12752551286084f; // (1/sqrt(128)) * log2(e)
  float x10 = bf2f(a.x), x11 = bf2f(a.y), x12 = bf2f(a.z), x13 = bf2f(a.w);
  float x20 = bf2f(b.x), x21 = bf2f(b.y), x22 = bf2f(b.z), x23 = bf2f(b.w);
  ushort4 o1, o2;
  o1.x = f2bf((x10 * c01.x - x20 * c01.y) * SC);
  o1.y = f2bf((x11 * c01.z - x21 * c01.w) * SC);
  o1.z = f2bf((x12 * c23.x - x22 * c23.y) * SC);
  o1.w = f2bf((x13 * c23.z - x23 * c23.w) * SC);
  o2.x = f2bf((x10 * c01.y + x20 * c01.x) * SC);
  o2.y = f2bf((x11 * c01.w + x21 * c01.z) * SC);
  o2.z = f2bf((x12 * c23.y + x22 * c23.x) * SC);
  o2.w = f2bf((x13 * c23.w + x23 * c23.z) * SC);
  u16* orow = Q + (((size_t)t * NH + h) << 7);
  *(ushort4*)(orow + d4) = o1;
  *(ushort4*)(orow + d4 + 64) = o2;
}

// ---------------- K conv(2)+rope: qkv bf16 -> K bf16 [S][NKV][128] ----------------
__global__ void convrope_k_kernel(const u16* __restrict__ qkv, const float* __restrict__ ck,
                                  const float* __restrict__ tab, u16* __restrict__ K) {
  int i = blockIdx.x * 256 + threadIdx.x; // S*NKV*16
  int d4 = (i & 15) * 4, kv = (i >> 4) & 7, t = i >> 7;
  const u16* cur = qkv + (size_t)t * 6144 + 4096 + kv * 128;
  float c0 = ck[kv * 2], c1 = ck[kv * 2 + 1];
  ushort4 a = *(const ushort4*)(cur + d4);
  ushort4 b = *(const ushort4*)(cur + d4 + 64);
  float x1[4] = { c1 * bf2f(a.x), c1 * bf2f(a.y), c1 * bf2f(a.z), c1 * bf2f(a.w) };
  float x2[4] = { c1 * bf2f(b.x), c1 * bf2f(b.y), c1 * bf2f(b.z), c1 * bf2f(b.w) };
  if (t > 0) {
    const u16* prv = cur - 6144;
    ushort4 pa = *(const ushort4*)(prv + d4);
    ushort4 pb = *(const ushort4*)(prv + d4 + 64);
    x1[0] += c0 * bf2f(pa.x); x1[1] += c0 * bf2f(pa.y); x1[2] += c0 * bf2f(pa.z); x1[3] += c0 * bf2f(pa.w);
    x2[0] += c0 * bf2f(pb.x); x2[1] += c0 * bf2f(pb.y); x2[2] += c0 * bf2f(pb.z); x2[3] += c0 * bf2f(pb.w);
  }
  const float4* tf = (const float4*)(tab + ((t << 6) + d4) * 2);
  float4 c01 = tf[0], c23 = tf[1];
  float cs[4] = { c01.x, c01.z, c23.x, c23.z };
  float sn[4] = { c01.y, c01.w, c23.y, c23.w };
  ushort4 o1, o2;
  o1.x = f2bf(x1[0] * cs[0] - x2[0] * sn[0]);
  o1.y = f2bf(x1[1] * cs[1] - x2[1] * sn[1]);
  o1.z = f2bf(x1[2] * cs[2] - x2[2] * sn[2]);
  o1.w = f2bf(x1[3] * cs[3] - x2[3] * sn[3]);
  o2.x = f2bf(x1[0] * sn[0] + x2[0] * cs[0]);
  o2.y = f2bf(x1[1] * sn[1] + x2[1] * cs[1]);
  o2.z = f2bf(x1[2] * sn[2] + x2[2] * cs[2]);
  o2.w = f2bf(x1[3] * sn[3] + x2[3] * cs[3]);
  u16* orow = K + (((size_t)t * NKV + kv) << 7);
  *(ushort4*)(orow + d4) = o1;
  *(ushort4*)(orow + d4 + 64) = o2;
}

// ---------------- V conv(2) + transpose: qkv bf16 -> VT bf16 [NKV][128][S] ----------------
__global__ __launch_bounds__(256) void convT_v_kernel(const u16* __restrict__ qkv,
                                                      const float* __restrict__ cv,
                                                      u16* __restrict__ VT) {
  __shared__ u16 ld[65][128];
  int tt = blockIdx.x * 64, kv = blockIdx.y;
  float c0 = cv[kv * 2], c1 = cv[kv * 2 + 1];
  for (int idx = threadIdx.x; idx < 65 * 32; idx += 256) {
    int r = idx >> 5, d4 = (idx & 31) * 4;
    int t = tt - 1 + r;
    ushort4 v = (t >= 0) ? *(const ushort4*)(qkv + (size_t)t * 6144 + 5120 + kv * 128 + d4)
                         : (ushort4){0, 0, 0, 0};
    *(ushort4*)(&ld[r][d4]) = v;
  }
  __syncthreads();
  int d = threadIdx.x >> 1, tc = (threadIdx.x & 1) * 32;
  u16* out = VT + ((size_t)kv * 128 + d) * S_LEN + tt + tc;
#pragma unroll
  for (int j = 0; j < 32; ++j)
    out[j] = f2bf(c0 * bf2f(ld[tc + j][d]) + c1 * bf2f(ld[tc + j + 1][d]));
}

// ---------------- NT GEMM: C[m,n] = sum_k A[m,k]*B[n,k]  (bf16 in, fp32 or bf16 out) ----------------
#define BM 128
#define BN 128
#define BK 64

template <bool BF16OUT>
__global__ __launch_bounds__(256, 2) void gemm_nt_kernel(const u16* __restrict__ A,
                                                         const u16* __restrict__ B,
                                                         void* __restrict__ C,
                                                         int M, int N, int K) {
  __shared__ __align__(16) u16 lA[BM * BK];
  __shared__ __align__(16) u16 lB[BN * BK];
  const int tid = threadIdx.x;
  const int wid = tid >> 6, lane = tid & 63;
  const int bm = blockIdx.y * BM, bn = blockIdx.x * BN;
  const int wr = (wid >> 1) * 64, wc = (wid & 1) * 64;
  const int lr = lane & 15, lg = lane >> 4;
  f32x4 acc[4][4] = {};
  const char* Ab = (const char*)A;
  const char* Bb = (const char*)B;
  const int nk = K / BK;
  for (int kt = 0; kt < nk; ++kt) {
    const size_t k0b = (size_t)kt * (BK * 2);
    __syncthreads();
#pragma unroll
    for (int i = 0; i < 4; ++i) {
      int off = (i * 4 + wid) * 1024 + lane * 16;
      int row = off >> 7, inrow = off & 127;
      int sw = inrow ^ ((row & 7) << 4);
      gload16(Ab + (size_t)(bm + row) * (K * 2) + k0b + sw, (char*)lA + (i * 4 + wid) * 1024);
      gload16(Bb + (size_t)(bn + row) * (K * 2) + k0b + sw, (char*)lB + (i * 4 + wid) * 1024);
    }
    __syncthreads();
    bf16x8 af[4][2], bfv[4][2];
#pragma unroll
    for (int m = 0; m < 4; ++m)
#pragma unroll
      for (int ks = 0; ks < 2; ++ks) {
        int row = wr + m * 16 + lr;
        int boff = row * 128 + ((ks * 64 + lg * 16) ^ ((row & 7) << 4));
        af[m][ks] = *(const bf16x8*)((const char*)lA + boff);
      }
#pragma unroll
    for (int n = 0; n < 4; ++n)
#pragma unroll
      for (int ks = 0; ks < 2; ++ks) {
        int row = wc + n * 16 + lr;
        int boff = row * 128 + ((ks * 64 + lg * 16) ^ ((row & 7) << 4));
        bfv[n][ks] = *(const bf16x8*)((const char*)lB + boff);
      }
#pragma unroll
    for (int m = 0; m < 4; ++m)
#pragma unroll
      for (int n = 0; n < 4; ++n)
#pragma unroll
        for (int ks = 0; ks < 2; ++ks)
          acc[m][n] = __builtin_amdgcn_mfma_f32_16x16x32_bf16(af[m][ks], bfv[n][ks], acc[m][n], 0, 0, 0);
  }
#pragma unroll
  for (int m = 0; m < 4; ++m)
#pragma unroll
    for (int n = 0; n < 4; ++n)
#pragma unroll
      for (int r = 0; r < 4; ++r) {
        int row = bm + wr + m * 16 + lg * 4 + r;
        int col = bn + wc + n * 16 + lr;
        if (BF16OUT)
          ((u16*)C)[(size_t)row * N + col] = f2bf(acc[m][n][r]);
        else
          ((float*)C)[(size_t)row * N + col] = acc[m][n][r];
      }
}

// ---------------- causal GQA flash attention (swapped QK^T, adjacent-pair fusion) ----------------
// Q: [S][NH][128] bf16 (pre-scaled by log2e/sqrt(D)), K: [S][NKV][128] bf16, VT: [NKV][128][S] bf16
// O: [S][NH*128] bf16.
// grid = 512 1-D blocks. Block g -> head h, tile-pair b: tiles qtA=2b, qtB=2b+1 (64 rows each).
// Size-complementary mapping: blocks g and g+256 have step counts summing to 34 (CU balance).
// Each wave owns 16 rows of tile A AND 16 rows of tile B; all steps except the last are fused,
// sharing every K/V LDS fragment read across both tiles.
__global__ __launch_bounds__(256, 2) void attn_kernel(const u16* __restrict__ Q,
                                                      const u16* __restrict__ K,
                                                      const u16* __restrict__ VT,
                                                      u16* __restrict__ O) {
  __shared__ __align__(16) u16 lK[2][64 * 128];   // [t][d], 256B rows, XOR swizzled
  __shared__ __align__(16) u16 lV[2][128 * 64];   // [d][t], 128B rows, XOR swizzled
  __shared__ __align__(16) u16 lP[4][2][16 * 64]; // per-wave P[q][k], 128B rows, XOR swizzled
  const int tid = threadIdx.x;
  const int wid = tid >> 6, lane = tid & 63;
  const int lr = lane & 15, lg = lane >> 4;
  const int g = blockIdx.x;
  const int s = g & 255;
  const int h = s >> 3, j = s & 7;
  const int b = (g < 256) ? (15 - j) : j;
  const int kvh = h >> 2;
  const int qtA = 2 * b, qtB = 2 * b + 1;
  const int qrowA = qtA * 64 + wid * 16 + lr;  // this lane's q-row for tile A (softmax layout)
  const int qrowB = qtB * 64 + wid * 16 + lr;

  bf16x8 qfA[4], qfB[4];
#pragma unroll
  for (int ks = 0; ks < 4; ++ks) {
    qfA[ks] = *(const bf16x8*)(Q + (((size_t)qrowA * NH + h) << 7) + ks * 32 + lg * 8);
    qfB[ks] = *(const bf16x8*)(Q + (((size_t)qrowB * NH + h) << 7) + ks * 32 + lg * 8);
  }

  f32x4 oA[8] = {}, oB[8] = {};
  float mA = -1e30f, sumA = 0.f, mB = -1e30f, sumB = 0.f;

  const char* Kb = (const char*)K;
  const char* Vb = (const char*)VT;
  char* pbA = (char*)lP[wid][0];
  char* pbB = (char*)lP[wid][1];

  auto stage = [&](int buf, int kt) {
    char* dK = (char*)lK[buf];
    char* dV = (char*)lV[buf];
#pragma unroll
    for (int i = 0; i < 4; ++i) {
      int off = (i * 4 + wid) * 1024 + lane * 16;
      int t = off >> 8, inrow = off & 255;
      gload16(Kb + (((size_t)((kt * 64 + t) * NKV + kvh)) << 8) + (inrow ^ ((t & 7) << 4)),
              dK + (i * 4 + wid) * 1024);
      int d = off >> 7, inr2 = off & 127;
      gload16(Vb + ((size_t)(kvh * 128 + d)) * (S_LEN * 2) + kt * 128 + (inr2 ^ ((d & 7) << 4)),
              dV + (i * 4 + wid) * 1024);
    }
  };

  // softmax on S^T fragments: lane holds 16 values (k = n*16+lg*4+r) for q-row `qrow`.
  auto smx = [&](f32x4* sv, float& mm, float& ll, f32x4* o, char* pbuf, bool diag, int qrow, int kt) {
    if (diag) {
#pragma unroll
      for (int n = 0; n < 4; ++n)
#pragma unroll
        for (int r = 0; r < 4; ++r) {
          int kg = kt * 64 + n * 16 + lg * 4 + r;
          if (kg > qrow) sv[n][r] = -1e30f;
        }
    }
    float pm = sv[0][0];
#pragma unroll
    for (int n = 0; n < 4; ++n)
#pragma unroll
      for (int r = 0; r < 4; ++r) pm = fmaxf(pm, sv[n][r]);
    pm = fmaxf(pm, __shfl_xor(pm, 16));
    pm = fmaxf(pm, __shfl_xor(pm, 32));
    if (__any(pm > mm + 8.f)) {
      float mn = fmaxf(mm, pm);
      float al = exp2f(mm - mn);
      mm = mn;
      ll *= al;
      float alo[4];
#pragma unroll
      for (int r = 0; r < 4; ++r) alo[r] = bcastf(al, lg * 4 + r);
#pragma unroll
      for (int nt = 0; nt < 8; ++nt)
#pragma unroll
        for (int r = 0; r < 4; ++r) o[nt][r] *= alo[r];
    }
    float rs = 0.f;
#pragma unroll
    for (int n = 0; n < 4; ++n)
#pragma unroll
      for (int r = 0; r < 4; ++r) {
        float p = exp2f(sv[n][r] - mm);
        sv[n][r] = p;
        rs += p;
      }
    rs += __shfl_xor(rs, 16);
    rs += __shfl_xor(rs, 32);
    ll += rs;
    // pack to bf16 pairs, write P[q=lr][k = n*16+lg*4 .. +3] as one b64
#pragma unroll
    for (int n = 0; n < 4; ++n) {
      uint2 w;
      w.x = cvtpk_bf16(sv[n][0], sv[n][1]);
      w.y = cvtpk_bf16(sv[n][2], sv[n][3]);
      *(uint2*)(pbuf + ((lr * 128 + n * 32 + lg * 8) ^ ((lr & 7) << 4))) = w;
    }
  };

  stage(0, 0);
  __syncthreads();
  for (int kt = 0; kt <= qtB; ++kt) {
    int cur = kt & 1;
    if (kt < qtB) stage(cur ^ 1, kt + 1);
    const char* kb = (const char*)lK[cur];
    const char* vb = (const char*)lV[cur];
    const bool doA = (kt <= qtA);

    // QK^T swapped: sv = mfma(K-frag as A, Q-frag as B) -> S^T[k][q], q = lr
    f32x4 svA[4], svB[4];
#pragma unroll
    for (int n = 0; n < 4; ++n) {
      f32x4 aA = {}, aB = {};
#pragma unroll
      for (int ks = 0; ks < 4; ++ks) {
        int trow = n * 16 + lr;
        int boff = trow * 256 + ((ks * 64 + lg * 16) ^ ((trow & 7) << 4));
        bf16x8 kf = *(const bf16x8*)(kb + boff);
        aB = __builtin_amdgcn_mfma_f32_16x16x32_bf16(kf, qfB[ks], aB, 0, 0, 0);
        aA = __builtin_amdgcn_mfma_f32_16x16x32_bf16(kf, qfA[ks], aA, 0, 0, 0);
      }
      svA[n] = aA; svB[n] = aB;
    }

    if (doA) smx(svA, mA, sumA, oA, pbA, kt == qtA, qrowA, kt);
    smx(svB, mB, sumB, oB, pbB, kt == qtB, qrowB, kt);

    // O += P * V ; V-frags shared across tiles
#pragma unroll
    for (int ks = 0; ks < 2; ++ks) {
      int poff = (lr * 128 + 64 * ks + 16 * lg) ^ ((lr & 7) << 4);
      bf16x8 pfB = *(const bf16x8*)(pbB + poff);
      bf16x8 pfA = *(const bf16x8*)(pbA + poff);
#pragma unroll
      for (int nt = 0; nt < 8; ++nt) {
        int drow = nt * 16 + lr;
        int vboff = drow * 128 + ((ks * 64 + lg * 16) ^ ((drow & 7) << 4));
        bf16x8 vf = *(const bf16x8*)(vb + vboff);
        oB[nt] = __builtin_amdgcn_mfma_f32_16x16x32_bf16(pfB, vf, oB[nt], 0, 0, 0);
        if (doA) oA[nt] = __builtin_amdgcn_mfma_f32_16x16x32_bf16(pfA, vf, oA[nt], 0, 0, 0);
      }
    }
    __syncthreads();
  }

  float riA = 1.0f / sumA, riB = 1.0f / sumB;
  float rA[4], rB[4];
#pragma unroll
  for (int r = 0; r < 4; ++r) {
    rA[r] = bcastf(riA, lg * 4 + r);
    rB[r] = bcastf(riB, lg * 4 + r);
  }
#pragma unroll
  for (int nt = 0; nt < 8; ++nt)
#pragma unroll
    for (int r = 0; r < 4; ++r) {
      int rowA = qtA * 64 + wid * 16 + lg * 4 + r;
      int rowB = qtB * 64 + wid * 16 + lg * 4 + r;
      int col = nt * 16 + lr;
      O[(size_t)rowA * 4096 + h * 128 + col] = f2bf(oA[nt][r] * rA[r]);
      O[(size_t)rowB * 4096 + h * 128 + col] = f2bf(oB[nt][r] * rB[r]);
    }
}

extern "C" void kernel_launch(void* const* d_in, const int* in_sizes, int n_in,
                              void* d_out, int out_size, void* d_ws, size_t ws_size,
                              hipStream_t stream) {
  const float* hidden = (const float*)d_in[0];
  const float* wpack  = (const float*)d_in[1];
  const float* wo     = (const float*)d_in[2];
  const float* convk  = (const float*)d_in[3];
  const float* convv  = (const float*)d_in[4];
  float* out = (float*)d_out;

  char* w = (char*)d_ws;
  u16*  hiddenB = (u16*)w;                   // 16,777,216 B (later reused as attn_out)
  u16*  wpackB  = (u16*)(w + 16777216);      // 50,331,648 B (later reused for w_o bf16)
  u16*  qkvB    = (u16*)(w + 67108864);      // 25,165,824 B (bf16 qkv)
  u16*  qrope   = (u16*)(w + 92274688);      // 16,777,216 B
  u16*  krope   = (u16*)(w + 109051904);     //  4,194,304 B
  u16*  vT      = (u16*)(w + 113246208);     //  4,194,304 B
  float* tab    = (float*)(w + 117440512);   //  1,048,576 B (float2 pairs)

  cvt4_kernel<<<8192, 256, 0, stream>>>(hidden, hiddenB, 2097152);
  cvt4_kernel<<<24576, 256, 0, stream>>>(wpack, wpackB, 6291456);
  rope_tab_kernel<<<512, 256, 0, stream>>>((float2*)tab);
  gemm_nt_kernel<true><<<dim3(48, 16), 256, 0, stream>>>(hiddenB, wpackB, qkvB, 2048, 6144, 4096);
  cvt4_kernel<<<16384, 256, 0, stream>>>(wo, wpackB, 4194304); // reuse wpackB for w_o bf16
  rope_q_kernel<<<4096, 256, 0, stream>>>(qkvB, tab, qrope);
  convrope_k_kernel<<<1024, 256, 0, stream>>>(qkvB, convk, tab, krope);
  convT_v_kernel<<<dim3(32, 8), 256, 0, stream>>>(qkvB, convv, vT);
  attn_kernel<<<512, 256, 0, stream>>>(qrope, krope, vT, hiddenB); // attn_out -> hiddenB
  gemm_nt_kernel<false><<<dim3(32, 16), 256, 0, stream>>>(hiddenB, wpackB, out, 2048, 4096, 4096);
}